// Round 8
// baseline (245.113 us; speedup 1.0000x reference)
//
#include <hip/hip_runtime.h>

// TranslationLayer: out[b,i,j] = in[b, i+dy[b], j-dx[b]] if in-bounds else 0
// B,H,W,C = 128,512,512,1 fp32. Pure memory-bound shift-gather.
//
// R9 (resubmit — container acquisition failed twice, kernel never ran):
// persistent grid-stride structure (m13 copy shape). R5..R8 proved the
// instruction scheme is irrelevant: DS funnel / 2 aligned loads / 1
// unaligned load / DPP funnel / NT-vs-plain store all land 223-227us.
// Last structural delta vs the 6.3 TB/s copy ubench and the 6.7 TB/s
// fills: those use FEW persistent workgroups; we used 32768 one-shot wgs
// (wave lifetime ~300ns, 1 load+store each, continuous launch/drain churn,
// no cross-group pipelining). This round: 2048 blocks = 8 wg/CU x 256 CU
// (exactly full occupancy, one dispatch wave), each block owns a contiguous
// 64KiB span = 32 rows of ONE sample -> b/dx/dy/s0/edge-class all hoisted;
// 16-iter loop, unroll 4 -> 4 loads in flight per wave. Body: 1 unaligned
// (4B-aligned) dwordx4 + 1 plain store + ~6 VALU.
// Zero-fill edges: per-element only in rare partial lanes (verified scheme
// from R6, absmax 0.0). Plain store (R7 A/B: NT neutral).

#define TB 128
#define TH 512
#define TW 512
#define W4 (TW / 4)          // 128 float4 groups per row
#define NBLK 2048            // 8 wg/CU * 256 CU
#define ITERS 16             // 4096 groups per block / 256 threads

typedef float f4  __attribute__((ext_vector_type(4)));
typedef float f4u __attribute__((ext_vector_type(4), aligned(4)));  // 4B-aligned view

__global__ __launch_bounds__(256) void TranslationLayer_63350767616318_kernel(
    const float* __restrict__ in,
    const int*   __restrict__ dx,
    const int*   __restrict__ dy,
    float*       __restrict__ out)
{
    const int tid  = threadIdx.x;
    const int b    = blockIdx.x >> 4;            // 16 blocks per sample
    const int i0   = (blockIdx.x & 15) << 5;     // first of 32 rows
    const int j4   = tid & (W4 - 1);
    const int half = tid >> 7;                   // 2 rows per iteration

    const int t   = -dx[b];                      // block-uniform -> SGPR
    const int dyb = dy[b];
    const int s0  = (j4 << 2) + t;               // source float idx in row
    const bool full = (s0 >= 0) & (s0 <= TW - 4);        // hoisted lane class
    const bool part = (s0 > -4) & (s0 < TW) & !full;

    const float* __restrict__ samp = in + (size_t)b * TH * TW;
    f4* __restrict__ outp = (f4*)out + ((size_t)blockIdx.x << 12) + tid;

    int i = i0 + half;
#pragma unroll 4
    for (int it = 0; it < ITERS; ++it, i += 2, outp += 256) {
        const int si = i + dyb;                  // wave-uniform row
        f4 res = (f4)(0.f);
        if ((unsigned)si < (unsigned)TH) {
            const float* __restrict__ row = samp + (size_t)si * TW;
            if (full) {
                res = *(const f4u*)(row + s0);   // one unaligned dwordx4
            } else if (part) {                   // rare row-edge lanes
#pragma unroll
                for (int e = 0; e < 4; ++e) {
                    const int s = s0 + e;
                    float x = 0.f;
                    if ((unsigned)s < (unsigned)TW) x = row[s];
                    res[e] = x;
                }
            }
        }
        *outp = res;                             // plain store (R7)
    }
}

extern "C" void kernel_launch(void* const* d_in, const int* in_sizes, int n_in,
                              void* d_out, int out_size, void* d_ws, size_t ws_size,
                              hipStream_t stream)
{
    const float* in  = (const float*)d_in[0];
    const int*   dx  = (const int*)d_in[1];
    const int*   dy  = (const int*)d_in[2];
    float*       out = (float*)d_out;

    // 8,388,608 float4 groups total; 2048 blocks * 256 threads * 16 iters
    dim3 grid(NBLK), block(256);
    TranslationLayer_63350767616318_kernel<<<grid, block, 0, stream>>>(in, dx, dy, out);
}

// Round 9
// 235.417 us; speedup vs baseline: 1.0412x; 1.0412x over previous
//
#include <hip/hip_runtime.h>

// TranslationLayer: out[b,i,j] = in[b, i+dy[b], j-dx[b]] if in-bounds else 0
// B,H,W,C = 128,512,512,1 fp32. Pure memory-bound shift-gather.
//
// R10: persistent + GRID-STRIDE (sweep without churn). R9 (persistent,
// block-contiguous) REGRESSED 64->86us kernel and finally exposed counters:
// FETCH=66MB (L3 serves half the reads -> true floor ~32us), VALU 3.9%,
// occupancy 66%, 2.3 TB/s. Diagnosis: R9 changed two variables at once —
// it removed dispatch churn but ALSO replaced the one-shot grid's sweeping
// contiguous access window (consecutive blocks = consecutive addresses,
// dispatched in order) with 2048 parked streams on scattered 64KiB regions
// (DRAM row thrash). The window was the asset, not the churn.
// This round keeps persistence, restores the sweep: grid-stride by 524288
// groups/iter. Algebra: i = ((blk&255)<<1)|half and j4 are ITERATION-
// INVARIANT; only b = (blk>>8) + 8*it changes. Device-wide each iteration
// touches one contiguous 8MB read + 8MB write window (= m13 copy shape).
// dx[b]/dy[b] remain block-uniform s_loads. Body: 1 unaligned (4B-aligned)
// dwordx4 + 1 plain store + ~10 VALU (R6-verified edge scheme, R7 store).

#define TB 128
#define TH 512
#define TW 512
#define W4 (TW / 4)              // 128 float4 groups per row
#define NBLK 2048                // 8 wg/CU * 256 CU
#define TOT4 (TB * TH * W4)      // 8,388,608 groups
#define ITERS (TOT4 / (NBLK * 256))   // 16

typedef float f4  __attribute__((ext_vector_type(4)));
typedef float f4u __attribute__((ext_vector_type(4), aligned(4)));  // 4B-aligned view

__global__ __launch_bounds__(256) void TranslationLayer_63350767616318_kernel(
    const float* __restrict__ in,
    const int*   __restrict__ dx,
    const int*   __restrict__ dy,
    float*       __restrict__ out)
{
    const int tid = threadIdx.x;
    const int blk = blockIdx.x;
    const int j4  = tid & (W4 - 1);
    const int i   = ((blk & 255) << 1) | (tid >> 7);   // row in sample: invariant
    int b         = blk >> 8;                          // sample: += 8 per iter

    f4* __restrict__ outp = (f4*)out + (size_t)blk * 256 + tid;

#pragma unroll 4
    for (int it = 0; it < ITERS; ++it, b += 8, outp += NBLK * 256) {
        const int t  = -dx[b];                         // block-uniform s_load
        const int si = i + dy[b];                      // wave-uniform row
        const int s0 = (j4 << 2) + t;                  // source float idx
        f4 res = (f4)(0.f);
        if ((unsigned)si < (unsigned)TH) {
            const float* __restrict__ row = in + ((size_t)b * TH + si) * TW;
            if (s0 >= 0 && s0 <= TW - 4) {
                res = *(const f4u*)(row + s0);         // one unaligned dwordx4
            } else if (s0 > -4 && s0 < TW) {           // rare row-edge lanes
#pragma unroll
                for (int e = 0; e < 4; ++e) {
                    const int s = s0 + e;
                    float x = 0.f;
                    if ((unsigned)s < (unsigned)TW) x = row[s];
                    res[e] = x;
                }
            }
        }
        *outp = res;                                   // plain store (R7)
    }
}

extern "C" void kernel_launch(void* const* d_in, const int* in_sizes, int n_in,
                              void* d_out, int out_size, void* d_ws, size_t ws_size,
                              hipStream_t stream)
{
    const float* in  = (const float*)d_in[0];
    const int*   dx  = (const int*)d_in[1];
    const int*   dy  = (const int*)d_in[2];
    float*       out = (float*)d_out;

    // 8,388,608 float4 groups; 2048 blocks * 256 threads * 16 grid-stride iters
    dim3 grid(NBLK), block(256);
    TranslationLayer_63350767616318_kernel<<<grid, block, 0, stream>>>(in, dx, dy, out);
}